// Round 23
// baseline (161.970 us; speedup 1.0000x reference)
//
#include <hip/hip_runtime.h>
#include <hip/hip_bf16.h>
#include <math.h>

#define B_ 4
#define N_ 4096
#define D_ 256
#define H_ 8
#define HD_ 32
#define TOKENS (B_ * N_)   // 16384
#define EPSF 1e-9f

typedef __bf16 bf16x8 __attribute__((ext_vector_type(8)));
typedef float f32x4 __attribute__((ext_vector_type(4)));
typedef ushort ushort8_t __attribute__((ext_vector_type(8)));

__device__ __forceinline__ float elu1(float x) { return x > 0.f ? x + 1.f : __expf(x); }

__device__ __forceinline__ ushort f2bf(float f) {
    __hip_bfloat16 h = __float2bfloat16(f);
    return *reinterpret_cast<ushort*>(&h);
}

#define GLOAD_LDS16(g, l)                                                              \
    __builtin_amdgcn_global_load_lds((__attribute__((address_space(1))) const void*)(g), \
                                     (__attribute__((address_space(3))) void*)(l), 16, 0, 0)

#define MFMA16(a, b, c) __builtin_amdgcn_mfma_f32_16x16x32_bf16((a), (b), (c), 0, 0, 0)

// ---------------- all four W matrices -> bf16, concatenated ----------------
__global__ __launch_bounds__(256) void k_cvt_w(const float* __restrict__ Wq,
                                               const float* __restrict__ Wk,
                                               const float* __restrict__ Wv,
                                               const float* __restrict__ Wo,
                                               ushort* __restrict__ dst) {
    const int i = blockIdx.x * 256 + threadIdx.x;  // 32768 threads x 8 els
    const int sel = i >> 13;
    const float* src = sel == 0 ? Wq : sel == 1 ? Wk : sel == 2 ? Wv : Wo;
    const int j = i & 8191;
    const float4* s = (const float4*)src + (size_t)j * 2;
    const float4 a = s[0], b = s[1];
    ushort8_t o;
    o[0] = f2bf(a.x); o[1] = f2bf(a.y); o[2] = f2bf(a.z); o[3] = f2bf(a.w);
    o[4] = f2bf(b.x); o[5] = f2bf(b.y); o[6] = f2bf(b.z); o[7] = f2bf(b.w);
    *((ushort8_t*)dst + i) = o;
}

// ================= K1: UNIFORM 512 blocks — qkv tile + fused prior stream =============
// Each block: 32-token qkv GEMM (round-10 proven) + bias for the SAME 32 rows.
// Bias nt-loads are issued one iteration EARLY and consumed one iteration LATE
// (T14 issue-early/consume-late): the consume waits vmcnt(6) (no W-queue drain),
// and the pre-compute barrier overlaps the bias-HBM and W-L2 latency windows.
// k,v stay on-chip; block emits qpre + an 8448-float kv/ksum partial (per-head MFMA).
__global__ __launch_bounds__(512, 4) void k_mix8(const float* __restrict__ prior,
                                                 const float* __restrict__ x,
                                                 const ushort* __restrict__ wq,
                                                 const ushort* __restrict__ wk,
                                                 const ushort* __restrict__ wv,
                                                 const float* __restrict__ bv,
                                                 float* __restrict__ bias_g,
                                                 ushort* __restrict__ qpre,
                                                 float* __restrict__ part) {
    __shared__ ushort As[32 * 256];       // 16 KB bf16 x-tile, XOR-swizzled
    __shared__ ushort Ws[3 * 256 * 32];   // 48 KB W slices; reused as VT/KT tiles later
    const int t = threadIdx.x;
    const int w = t >> 6, lane = t & 63;
    const int qidx = blockIdx.x;          // 0..511
    const int rowBase = qidx * 32;

    // ---- stage x (fp32 -> bf16, swizzled) ----
    {
        const int r = t >> 4;             // 0..31
        const int c0 = (t & 15) * 4;      // 0..60
#pragma unroll
        for (int j = 0; j < 4; ++j) {
            const int c = c0 + j * 64;
            const float4 xv = *(const float4*)(x + (size_t)(rowBase + r) * 256 + c);
            ushort4 o;
            o.x = f2bf(xv.x); o.y = f2bf(xv.y); o.z = f2bf(xv.z); o.w = f2bf(xv.w);
            const int byte = (r * 512 + c * 2) ^ ((r & 7) << 4);
            *(ushort4*)((char*)As + byte) = o;
        }
    }

    // ---- bias stream state: wave w owns rows rowBase + w*4 .. +3 ----
    const int brow0 = rowBase + w * 4;
    const f32x4* bp = (const f32x4*)(prior + (size_t)brow0 * N_);  // 4 rows x 1024 f32x4
    float s0 = 0.f, s1 = 0.f, s2 = 0.f, s3 = 0.f;
    f32x4 bb0, bb1, bb2, bb3, bb4, bb5, bb6, bb7;

#define BIAS_ISSUE(IT)                                                          \
    {                                                                           \
        const f32x4* rp_ = bp + ((IT) >> 1) * 1024 + ((IT) & 1) * 512 + lane;   \
        bb0 = __builtin_nontemporal_load(rp_ + 0 * 64);                         \
        bb1 = __builtin_nontemporal_load(rp_ + 1 * 64);                         \
        bb2 = __builtin_nontemporal_load(rp_ + 2 * 64);                         \
        bb3 = __builtin_nontemporal_load(rp_ + 3 * 64);                         \
        bb4 = __builtin_nontemporal_load(rp_ + 4 * 64);                         \
        bb5 = __builtin_nontemporal_load(rp_ + 5 * 64);                         \
        bb6 = __builtin_nontemporal_load(rp_ + 6 * 64);                         \
        bb7 = __builtin_nontemporal_load(rp_ + 7 * 64);                         \
    }
#define BIAS_CONSUME(IT)                                                        \
    {                                                                           \
        float ps_ = (bb0[0] + bb0[1] + bb0[2] + bb0[3]) +                       \
                    (bb1[0] + bb1[1] + bb1[2] + bb1[3]) +                       \
                    (bb2[0] + bb2[1] + bb2[2] + bb2[3]) +                       \
                    (bb3[0] + bb3[1] + bb3[2] + bb3[3]) +                       \
                    (bb4[0] + bb4[1] + bb4[2] + bb4[3]) +                       \
                    (bb5[0] + bb5[1] + bb5[2] + bb5[3]) +                       \
                    (bb6[0] + bb6[1] + bb6[2] + bb6[3]) +                       \
                    (bb7[0] + bb7[1] + bb7[2] + bb7[3]);                        \
        const int br_ = (IT) >> 1;                                              \
        if (br_ == 0) s0 += ps_;                                                \
        else if (br_ == 1) s1 += ps_;                                           \
        else if (br_ == 2) s2 += ps_;                                           \
        else s3 += ps_;                                                         \
    }

    BIAS_ISSUE(0)   // prologue: iteration-0 bias loads in flight

    const int wr = w >> 2, wc = w & 3;    // 2 x 4 waves; wave tile 16 rows x 64 cols
    const int q_ = lane >> 4;             // k-quarter 0..3
    f32x4 accq[4] = {}, acck[4] = {}, accv[4] = {};

#pragma unroll
    for (int it = 0; it < 8; ++it) {
        const int kt = it * 32;
        __syncthreads();   // Ws reuse fence (covers A-stage on first iter)
#pragma unroll
        for (int j = 0; j < 6; ++j) {
            const int c = j * 512 + t;            // 0..3071
            const int idx = c & 1023;
            const int e = idx >> 2;
            const int pslot = idx & 3;
            const int qsrc = pslot ^ ((e >> 1) & 3);
            const ushort* srcm = (j < 2) ? wq : (j < 4) ? wk : wv;
            GLOAD_LDS16(srcm + (size_t)e * 256 + kt + qsrc * 8, (char*)Ws + c * 16);
        }
        // consume bias(it) — issued one iter ago, older than this iter's gloads
        BIAS_CONSUME(it)
        // issue bias(it+1) — youngest in queue; overlaps W latency at the barrier
        if (it < 7) BIAS_ISSUE(it + 1)
        __syncthreads();
        const int r = wr * 16 + (lane & 15);
        const int abyte = (r * 512 + (kt + q_ * 8) * 2) ^ ((r & 7) << 4);
        const bf16x8 af = *(const bf16x8*)((const char*)As + abyte);
#pragma unroll
        for (int n = 0; n < 4; ++n) {
            const int e = wc * 64 + n * 16 + (lane & 15);
            const int wbyte = e * 64 + ((q_ ^ ((e >> 1) & 3)) * 16);
            const bf16x8 bq = *(const bf16x8*)((const char*)Ws + wbyte);
            const bf16x8 bk = *(const bf16x8*)((const char*)Ws + 16384 + wbyte);
            const bf16x8 bw = *(const bf16x8*)((const char*)Ws + 32768 + wbyte);
            accq[n] = MFMA16(af, bq, accq[n]);
            acck[n] = MFMA16(af, bk, acck[n]);
            accv[n] = MFMA16(af, bw, accv[n]);
        }
    }
#undef BIAS_ISSUE
#undef BIAS_CONSUME

    // ---- bias finalize: wave-reduce each of the 4 row-sums ----
#define BIAS_RED(sv, rr)                                                    \
    {                                                                       \
        float v_ = sv;                                                      \
        for (int off = 32; off; off >>= 1) v_ += __shfl_xor(v_, off, 64);   \
        if (lane == 0) bias_g[brow0 + rr] = v_ * (1.0f / N_);               \
    }
    BIAS_RED(s0, 0) BIAS_RED(s1, 1) BIAS_RED(s2, 2) BIAS_RED(s3, 3)
#undef BIAS_RED

    __syncthreads();   // all waves done reading Ws before overlaying VT/KT

    // ---- epilogue: qpre to global; k,v (activated, bf16) into LDS tiles ----
    ushort* VT = Ws;
    ushort* KT = Ws + 8192;
#pragma unroll
    for (int n = 0; n < 4; ++n)
#pragma unroll
        for (int j = 0; j < 4; ++j) {
            const int rl = wr * 16 + (lane >> 4) * 4 + j;    // token t in tile
            const int col = wc * 64 + n * 16 + (lane & 15);  // 0..255
            const size_t go = (size_t)(rowBase + rl) * 256 + col;
            qpre[go] = f2bf(accq[n][j]);
            const int head = col >> 5, dm = col & 31;
            KT[head * 1024 + dm * 32 + rl] = f2bf(elu1(acck[n][j]));
            VT[head * 1024 + dm * 32 + rl] = f2bf(elu1(accv[n][j] + bv[col]));
        }
    __syncthreads();

    // ---- kv partial via MFMA: wave w = head w ----
    const ushort* vtw = VT + w * 1024;
    const ushort* ktw = KT + w * 1024;
    bf16x8 av[2], bk2[2];
#pragma unroll
    for (int i = 0; i < 2; ++i) {
        av[i]  = *(const bf16x8*)(vtw + (i * 16 + (lane & 15)) * 32 + (lane >> 4) * 8);
        bk2[i] = *(const bf16x8*)(ktw + (i * 16 + (lane & 15)) * 32 + (lane >> 4) * 8);
    }
    bf16x8 ones;
#pragma unroll
    for (int i = 0; i < 8; ++i) ones[i] = (__bf16)1.0f;
    f32x4 kvacc[2][2] = {};
    f32x4 ks[2] = {};
#pragma unroll
    for (int mi = 0; mi < 2; ++mi)
#pragma unroll
        for (int di = 0; di < 2; ++di)
            kvacc[mi][di] = MFMA16(av[mi], bk2[di], kvacc[mi][di]);
#pragma unroll
    for (int di = 0; di < 2; ++di) ks[di] = MFMA16(ones, bk2[di], ks[di]);

    float* pp = part + (size_t)qidx * 8448 + w * 1056;
#pragma unroll
    for (int mi = 0; mi < 2; ++mi)
#pragma unroll
        for (int di = 0; di < 2; ++di)
#pragma unroll
            for (int j = 0; j < 4; ++j) {
                const int m = mi * 16 + (lane >> 4) * 4 + j;
                const int d = di * 16 + (lane & 15);
                pp[m * 32 + d] = kvacc[mi][di][j];
            }
    if ((lane >> 4) == 0) {
        pp[1024 + (lane & 15)] = ks[0][0];
        pp[1024 + 16 + (lane & 15)] = ks[1][0];
    }
}

// ---------------- reduce 128 chunk-partials per (b,h); kv -> bf16, ksum -> fp32 ------
__global__ __launch_bounds__(256) void k_kvred(const float* __restrict__ part,
                                               ushort* __restrict__ kvbf,
                                               float* __restrict__ ksum) {
    const int i = blockIdx.x * 256 + threadIdx.x;   // 0..33791 (132*256)
    if (i >= 32 * 1056) return;
    const int bh = i / 1056, r = i - bh * 1056;
    const int b = bh >> 3, h = bh & 7;
    float s = 0.f;
#pragma unroll 8
    for (int c = 0; c < 128; ++c)
        s += part[(size_t)(b * 128 + c) * 8448 + h * 1056 + r];
    if (r < 1024) kvbf[(size_t)bh * 1024 + r] = f2bf(s);
    else          ksum[(size_t)bh * 32 + (r - 1024)] = s;
}

// ================= K3: q-finalize + MFMA attn + out-GEMM =================
__global__ __launch_bounds__(512, 2) void k_fusedB(const ushort* __restrict__ qpre,
                                                   const float* __restrict__ bias_g,
                                                   const ushort* __restrict__ kvbf,
                                                   const float* __restrict__ ksum,
                                                   const ushort* __restrict__ wo,
                                                   const float* __restrict__ bo,
                                                   float* __restrict__ out) {
    __shared__ ushort qs[64 * 256];    // linear bf16 q tile (32 KB)
    __shared__ ushort at_s[64 * 256];  // swizzled bf16 attn tile (32 KB)
    __shared__ ushort Ws2[256 * 32];   // 16 KB wo slice, slot-swizzled
    __shared__ float den_s[64][8];     // 2 KB
    const int t = threadIdx.x;
    const int w = t >> 6, lane = t & 63;
    const int tokBase = blockIdx.x * 64;
    const int b = tokBase >> 12;

#pragma unroll
    for (int j = 0; j < 4; ++j) {
        const int chunk = j * 512 + t;
        GLOAD_LDS16(qpre + (size_t)tokBase * 256 + (size_t)chunk * 8,
                    (char*)qs + chunk * 16);
    }
    __syncthreads();

    // ---- q finalize in-place ----
    {
        const int r = t >> 3;
        const float brow = bias_g[tokBase + r];
        const int cb = (t & 7) * 32;
#pragma unroll
        for (int i = 0; i < 4; ++i) {
            bf16x8 qv = *(bf16x8*)(qs + r * 256 + cb + i * 8);
#pragma unroll
            for (int j = 0; j < 8; ++j) qv[j] = (__bf16)elu1((float)qv[j] + brow);
            *(bf16x8*)(qs + r * 256 + cb + i * 8) = qv;
        }
    }
    __syncthreads();

    // ---- denominator: den_s[tok][h] = q[tok][h,:] . ksum[b,h,:] + eps ----
    {
        const int tok = t >> 3, h = t & 7;
        const float* ksp = ksum + (size_t)(b * H_ + h) * HD_;
        float den = 0.f;
#pragma unroll
        for (int i = 0; i < 4; ++i) {
            const bf16x8 qv = *(const bf16x8*)(qs + tok * 256 + h * HD_ + i * 8);
            const f32x4 k0 = *(const f32x4*)(ksp + i * 8);
            const f32x4 k1 = *(const f32x4*)(ksp + i * 8 + 4);
#pragma unroll
            for (int j = 0; j < 4; ++j) {
                den = fmaf((float)qv[j], k0[j], den);
                den = fmaf((float)qv[j + 4], k1[j], den);
            }
        }
        den_s[tok][h] = den + EPSF;
    }

    // ---- numerator via MFMA: wave w = head w; Q[64x32] x kv_h[32x32]^T ----
    bf16x8 af[4], bfk[2];
#pragma unroll
    for (int mi = 0; mi < 4; ++mi)
        af[mi] = *(const bf16x8*)(qs + (mi * 16 + (lane & 15)) * 256 + w * HD_ +
                                  (lane >> 4) * 8);
#pragma unroll
    for (int ni = 0; ni < 2; ++ni)
        bfk[ni] = *(const bf16x8*)(kvbf +
                                   ((size_t)(b * H_ + w) * HD_ + ni * 16 + (lane & 15)) * HD_ +
                                   (lane >> 4) * 8);
    f32x4 nacc[4][2] = {};
#pragma unroll
    for (int mi = 0; mi < 4; ++mi)
#pragma unroll
        for (int ni = 0; ni < 2; ++ni)
            nacc[mi][ni] = MFMA16(af[mi], bfk[ni], nacc[mi][ni]);

    __syncthreads();   // den_s visible to all waves

    // ---- divide + write swizzled at_s ----
#pragma unroll
    for (int mi = 0; mi < 4; ++mi)
#pragma unroll
        for (int ni = 0; ni < 2; ++ni)
#pragma unroll
            for (int j = 0; j < 4; ++j) {
                const int tok = mi * 16 + (lane >> 4) * 4 + j;
                const int c2 = w * HD_ + ni * 16 + (lane & 15);
                const float a = nacc[mi][ni][j] / den_s[tok][w];
                const int byte = (tok * 512 + c2 * 2) ^ ((tok & 7) << 4);
                *(ushort*)((char*)at_s + byte) = f2bf(a);
            }

    // ---- out GEMM: 8 waves (2x4), wave tile 32 rows x 64 cols; wo from LDS ----
    const int wr = w >> 2, wc = w & 3;
    const int q_ = lane >> 4;
    f32x4 acc[2][4] = {};
    for (int kt = 0; kt < 256; kt += 32) {
        __syncthreads();   // first iteration also covers at_s writes
#pragma unroll
        for (int j = 0; j < 2; ++j) {
            const int ch = j * 512 + t;           // 0..1023
            const int e = ch >> 2;
            const int pslot = ch & 3;
            const int qsrc = pslot ^ ((e >> 1) & 3);
            GLOAD_LDS16(wo + (size_t)e * 256 + kt + qsrc * 8, (char*)Ws2 + ch * 16);
        }
        __syncthreads();
        bf16x8 af2[2];
#pragma unroll
        for (int mm = 0; mm < 2; ++mm) {
            const int r = wr * 32 + mm * 16 + (lane & 15);
            const int byte = (r * 512 + (kt + q_ * 8) * 2) ^ ((r & 7) << 4);
            af2[mm] = *(const bf16x8*)((const char*)at_s + byte);
        }
#pragma unroll
        for (int n = 0; n < 4; ++n) {
            const int e = wc * 64 + n * 16 + (lane & 15);
            const int wbyte = e * 64 + ((q_ ^ ((e >> 1) & 3)) * 16);
            const bf16x8 bw = *(const bf16x8*)((const char*)Ws2 + wbyte);
#pragma unroll
            for (int mm = 0; mm < 2; ++mm)
                acc[mm][n] = MFMA16(af2[mm], bw, acc[mm][n]);
        }
    }
#pragma unroll
    for (int mm = 0; mm < 2; ++mm)
#pragma unroll
        for (int n = 0; n < 4; ++n)
#pragma unroll
            for (int j = 0; j < 4; ++j) {
                const int row = tokBase + wr * 32 + mm * 16 + (lane >> 4) * 4 + j;
                const int col = wc * 64 + n * 16 + (lane & 15);
                out[(size_t)row * 256 + col] = acc[mm][n][j] + bo[col];
            }
}

extern "C" void kernel_launch(void* const* d_in, const int* in_sizes, int n_in,
                              void* d_out, int out_size, void* d_ws, size_t ws_size,
                              hipStream_t stream) {
    const float* x     = (const float*)d_in[0];
    const float* prior = (const float*)d_in[1];
    const float* Wq    = (const float*)d_in[2];
    const float* Wk    = (const float*)d_in[3];
    const float* Wv    = (const float*)d_in[4];
    const float* bv    = (const float*)d_in[5];
    const float* Wo    = (const float*)d_in[6];
    const float* bo    = (const float*)d_in[7];
    float* out = (float*)d_out;

    // workspace layout (round-22 verbatim)
    char* w8 = (char*)d_ws;
    ushort* qpre = (ushort*)w8;                         // 8 MB bf16
    ushort* wqb  = qpre + (size_t)TOKENS * D_;          // 4 x 128 KB bf16
    ushort* wkb  = wqb + 65536;
    ushort* wvb  = wkb + 65536;
    ushort* wob  = wvb + 65536;
    ushort* kvbf = wob + 65536;                         // 64 KB bf16 kv summary
    float* ksb   = (float*)(kvbf + 32768);              // 4 KB
    float* bias  = ksb + 1024;                          // 64 KB
    float* part  = bias + TOKENS;                       // 512*8448*4 = 17.3 MB

    k_cvt_w<<<128, 256, 0, stream>>>(Wq, Wk, Wv, Wo, wqb);

    k_mix8<<<512, 512, 0, stream>>>(prior, x, wqb, wkb, wvb, bv, bias, qpre, part);

    k_kvred<<<132, 256, 0, stream>>>(part, kvbf, ksb);

    k_fusedB<<<256, 512, 0, stream>>>(qpre, bias, kvbf, ksb, wob, bo, out);
}

// Round 24
// 92.228 us; speedup vs baseline: 1.7562x; 1.7562x over previous
//
#include <hip/hip_runtime.h>
#include <hip/hip_bf16.h>
#include <math.h>

#define B_ 4
#define N_ 4096
#define D_ 256
#define H_ 8
#define HD_ 32
#define TOKENS (B_ * N_)   // 16384
#define EPSF 1e-9f

typedef __bf16 bf16x8 __attribute__((ext_vector_type(8)));
typedef float f32x4 __attribute__((ext_vector_type(4)));
typedef ushort ushort8_t __attribute__((ext_vector_type(8)));

__device__ __forceinline__ float elu1(float x) { return x > 0.f ? x + 1.f : __expf(x); }

__device__ __forceinline__ ushort f2bf(float f) {
    __hip_bfloat16 h = __float2bfloat16(f);
    return *reinterpret_cast<ushort*>(&h);
}

#define GLOAD_LDS16(g, l)                                                              \
    __builtin_amdgcn_global_load_lds((__attribute__((address_space(1))) const void*)(g), \
                                     (__attribute__((address_space(3))) void*)(l), 16, 0, 0)

#define MFMA16(a, b, c) __builtin_amdgcn_mfma_f32_16x16x32_bf16((a), (b), (c), 0, 0, 0)

// ---------------- all four W matrices -> bf16, concatenated ----------------
__global__ __launch_bounds__(256) void k_cvt_w(const float* __restrict__ Wq,
                                               const float* __restrict__ Wk,
                                               const float* __restrict__ Wv,
                                               const float* __restrict__ Wo,
                                               ushort* __restrict__ dst) {
    const int i = blockIdx.x * 256 + threadIdx.x;  // 32768 threads x 8 els
    const int sel = i >> 13;
    const float* src = sel == 0 ? Wq : sel == 1 ? Wk : sel == 2 ? Wv : Wo;
    const int j = i & 8191;
    const float4* s = (const float4*)src + (size_t)j * 2;
    const float4 a = s[0], b = s[1];
    ushort8_t o;
    o[0] = f2bf(a.x); o[1] = f2bf(a.y); o[2] = f2bf(a.z); o[3] = f2bf(a.w);
    o[4] = f2bf(b.x); o[5] = f2bf(b.y); o[6] = f2bf(b.z); o[7] = f2bf(b.w);
    *((ushort8_t*)dst + i) = o;
}

// ================= K1: hetero (round-10 proven) + fused kv-partials ==================
__global__ __launch_bounds__(512, 2) void k_mix2(const float* __restrict__ prior,
                                                 const float* __restrict__ x,
                                                 const ushort* __restrict__ wq,
                                                 const ushort* __restrict__ wk,
                                                 const ushort* __restrict__ wv,
                                                 const float* __restrict__ bv,
                                                 float* __restrict__ bias_g,
                                                 ushort* __restrict__ qpre,
                                                 float* __restrict__ part) {
    __shared__ ushort As[32 * 256];       // 16 KB bf16 x-tile, XOR-swizzled
    __shared__ ushort Ws[3 * 256 * 32];   // 48 KB W slices; reused as VT/KT tiles later
    const int t = threadIdx.x;
    const int w = t >> 6, lane = t & 63;
    const int bid = blockIdx.x;

    if (bid % 5 != 0) {
        // ---- bias block: wave w sums row bidx*8+w (16 KB) with nt loads ----
        const int bidx = bid - bid / 5 - 1;           // 0..2047
        const int row = bidx * 8 + w;
        const f32x4* p = (const f32x4*)(prior + (size_t)row * N_);
        float s0 = 0.f, s1 = 0.f, s2 = 0.f, s3 = 0.f;
#pragma unroll
        for (int i = 0; i < 4; ++i) {
            const f32x4 a = __builtin_nontemporal_load(p + (i * 4 + 0) * 64 + lane);
            const f32x4 b = __builtin_nontemporal_load(p + (i * 4 + 1) * 64 + lane);
            const f32x4 c = __builtin_nontemporal_load(p + (i * 4 + 2) * 64 + lane);
            const f32x4 d = __builtin_nontemporal_load(p + (i * 4 + 3) * 64 + lane);
            s0 += a[0] + a[1] + a[2] + a[3];
            s1 += b[0] + b[1] + b[2] + b[3];
            s2 += c[0] + c[1] + c[2] + c[3];
            s3 += d[0] + d[1] + d[2] + d[3];
        }
        float s = (s0 + s1) + (s2 + s3);
#pragma unroll
        for (int off = 32; off; off >>= 1) s += __shfl_xor(s, off, 64);
        if (lane == 0) bias_g[row] = s * (1.0f / N_);
        return;
    }

    // ---- qkv GEMM tile (round-10 proven body) ----
    const int qidx = bid / 5;             // 0..511
    const int rowBase = qidx * 32;

    {
        const int r = t >> 4;             // 0..31
        const int c0 = (t & 15) * 4;      // 0..60
#pragma unroll
        for (int j = 0; j < 4; ++j) {
            const int c = c0 + j * 64;
            const float4 xv = *(const float4*)(x + (size_t)(rowBase + r) * 256 + c);
            ushort4 o;
            o.x = f2bf(xv.x); o.y = f2bf(xv.y); o.z = f2bf(xv.z); o.w = f2bf(xv.w);
            const int byte = (r * 512 + c * 2) ^ ((r & 7) << 4);
            *(ushort4*)((char*)As + byte) = o;
        }
    }

    const int wr = w >> 2, wc = w & 3;    // 2 x 4 waves; wave tile 16 rows x 64 cols
    const int q_ = lane >> 4;             // k-quarter 0..3
    f32x4 accq[4] = {}, acck[4] = {}, accv[4] = {};

    for (int kt = 0; kt < 256; kt += 32) {
        __syncthreads();   // also covers the A-stage on first iteration
#pragma unroll
        for (int j = 0; j < 6; ++j) {
            const int c = j * 512 + t;            // 0..3071
            const int idx = c & 1023;
            const int e = idx >> 2;
            const int pslot = idx & 3;
            const int qsrc = pslot ^ ((e >> 1) & 3);
            const ushort* srcm = (j < 2) ? wq : (j < 4) ? wk : wv;
            GLOAD_LDS16(srcm + (size_t)e * 256 + kt + qsrc * 8, (char*)Ws + c * 16);
        }
        __syncthreads();
        const int r = wr * 16 + (lane & 15);
        const int abyte = (r * 512 + (kt + q_ * 8) * 2) ^ ((r & 7) << 4);
        const bf16x8 af = *(const bf16x8*)((const char*)As + abyte);
#pragma unroll
        for (int n = 0; n < 4; ++n) {
            const int e = wc * 64 + n * 16 + (lane & 15);
            const int wbyte = e * 64 + ((q_ ^ ((e >> 1) & 3)) * 16);
            const bf16x8 bq = *(const bf16x8*)((const char*)Ws + wbyte);
            const bf16x8 bk = *(const bf16x8*)((const char*)Ws + 16384 + wbyte);
            const bf16x8 bw = *(const bf16x8*)((const char*)Ws + 32768 + wbyte);
            accq[n] = MFMA16(af, bq, accq[n]);
            acck[n] = MFMA16(af, bk, acck[n]);
            accv[n] = MFMA16(af, bw, accv[n]);
        }
    }

    __syncthreads();   // all waves done reading Ws before overlaying VT/KT

    // ---- epilogue: qpre to global; k,v (activated, bf16) into LDS tiles ----
    ushort* VT = Ws;
    ushort* KT = Ws + 8192;
#pragma unroll
    for (int n = 0; n < 4; ++n)
#pragma unroll
        for (int j = 0; j < 4; ++j) {
            const int rl = wr * 16 + (lane >> 4) * 4 + j;    // token t in tile
            const int col = wc * 64 + n * 16 + (lane & 15);  // 0..255
            const size_t go = (size_t)(rowBase + rl) * 256 + col;
            qpre[go] = f2bf(accq[n][j]);
            const int head = col >> 5, dm = col & 31;
            KT[head * 1024 + dm * 32 + rl] = f2bf(elu1(acck[n][j]));
            VT[head * 1024 + dm * 32 + rl] = f2bf(elu1(accv[n][j] + bv[col]));
        }
    __syncthreads();

    // ---- kv partial via MFMA: wave w = head w ----
    const ushort* vtw = VT + w * 1024;
    const ushort* ktw = KT + w * 1024;
    bf16x8 av[2], bk2[2];
#pragma unroll
    for (int i = 0; i < 2; ++i) {
        av[i]  = *(const bf16x8*)(vtw + (i * 16 + (lane & 15)) * 32 + (lane >> 4) * 8);
        bk2[i] = *(const bf16x8*)(ktw + (i * 16 + (lane & 15)) * 32 + (lane >> 4) * 8);
    }
    bf16x8 ones;
#pragma unroll
    for (int i = 0; i < 8; ++i) ones[i] = (__bf16)1.0f;
    f32x4 kvacc[2][2] = {};
    f32x4 ks[2] = {};
#pragma unroll
    for (int mi = 0; mi < 2; ++mi)
#pragma unroll
        for (int di = 0; di < 2; ++di)
            kvacc[mi][di] = MFMA16(av[mi], bk2[di], kvacc[mi][di]);
#pragma unroll
    for (int di = 0; di < 2; ++di) ks[di] = MFMA16(ones, bk2[di], ks[di]);

    float* pp = part + (size_t)qidx * 8448 + w * 1056;
#pragma unroll
    for (int mi = 0; mi < 2; ++mi)
#pragma unroll
        for (int di = 0; di < 2; ++di)
#pragma unroll
            for (int j = 0; j < 4; ++j) {
                const int m = mi * 16 + (lane >> 4) * 4 + j;
                const int d = di * 16 + (lane & 15);
                pp[m * 32 + d] = kvacc[mi][di][j];
            }
    if ((lane >> 4) == 0) {
        pp[1024 + (lane & 15)] = ks[0][0];
        pp[1024 + 16 + (lane & 15)] = ks[1][0];
    }
}

// ---------------- reduce 128 chunk-partials per (b,h); kv -> bf16, ksum -> fp32 ------
__global__ __launch_bounds__(256) void k_kvred(const float* __restrict__ part,
                                               ushort* __restrict__ kvbf,
                                               float* __restrict__ ksum) {
    const int i = blockIdx.x * 256 + threadIdx.x;   // 0..33791 (132*256)
    if (i >= 32 * 1056) return;
    const int bh = i / 1056, r = i - bh * 1056;
    const int b = bh >> 3, h = bh & 7;
    float s = 0.f;
#pragma unroll 8
    for (int c = 0; c < 128; ++c)
        s += part[(size_t)(b * 128 + c) * 8448 + h * 1056 + r];
    if (r < 1024) kvbf[(size_t)bh * 1024 + r] = f2bf(s);
    else          ksum[(size_t)bh * 32 + (r - 1024)] = s;
}

// ================= K3: q-finalize + MFMA attn + out-GEMM =================
__global__ __launch_bounds__(512, 2) void k_fusedB(const ushort* __restrict__ qpre,
                                                   const float* __restrict__ bias_g,
                                                   const ushort* __restrict__ kvbf,
                                                   const float* __restrict__ ksum,
                                                   const ushort* __restrict__ wo,
                                                   const float* __restrict__ bo,
                                                   float* __restrict__ out) {
    __shared__ ushort qs[64 * 256];    // linear bf16 q tile (32 KB)
    __shared__ ushort at_s[64 * 256];  // swizzled bf16 attn tile (32 KB)
    __shared__ ushort Ws2[256 * 32];   // 16 KB wo slice, slot-swizzled
    __shared__ float den_s[64][8];     // 2 KB
    const int t = threadIdx.x;
    const int w = t >> 6, lane = t & 63;
    const int tokBase = blockIdx.x * 64;
    const int b = tokBase >> 12;

#pragma unroll
    for (int j = 0; j < 4; ++j) {
        const int chunk = j * 512 + t;
        GLOAD_LDS16(qpre + (size_t)tokBase * 256 + (size_t)chunk * 8,
                    (char*)qs + chunk * 16);
    }
    __syncthreads();

    // ---- q finalize in-place ----
    {
        const int r = t >> 3;
        const float brow = bias_g[tokBase + r];
        const int cb = (t & 7) * 32;
#pragma unroll
        for (int i = 0; i < 4; ++i) {
            bf16x8 qv = *(bf16x8*)(qs + r * 256 + cb + i * 8);
#pragma unroll
            for (int j = 0; j < 8; ++j) qv[j] = (__bf16)elu1((float)qv[j] + brow);
            *(bf16x8*)(qs + r * 256 + cb + i * 8) = qv;
        }
    }
    __syncthreads();

    // ---- denominator: den_s[tok][h] = q[tok][h,:] . ksum[b,h,:] + eps ----
    {
        const int tok = t >> 3, h = t & 7;
        const float* ksp = ksum + (size_t)(b * H_ + h) * HD_;
        float den = 0.f;
#pragma unroll
        for (int i = 0; i < 4; ++i) {
            const bf16x8 qv = *(const bf16x8*)(qs + tok * 256 + h * HD_ + i * 8);
            const f32x4 k0 = *(const f32x4*)(ksp + i * 8);
            const f32x4 k1 = *(const f32x4*)(ksp + i * 8 + 4);
#pragma unroll
            for (int j = 0; j < 4; ++j) {
                den = fmaf((float)qv[j], k0[j], den);
                den = fmaf((float)qv[j + 4], k1[j], den);
            }
        }
        den_s[tok][h] = den + EPSF;
    }

    // ---- numerator via MFMA: wave w = head w; Q[64x32] x kv_h[32x32]^T ----
    bf16x8 af[4], bfk[2];
#pragma unroll
    for (int mi = 0; mi < 4; ++mi)
        af[mi] = *(const bf16x8*)(qs + (mi * 16 + (lane & 15)) * 256 + w * HD_ +
                                  (lane >> 4) * 8);
#pragma unroll
    for (int ni = 0; ni < 2; ++ni)
        bfk[ni] = *(const bf16x8*)(kvbf +
                                   ((size_t)(b * H_ + w) * HD_ + ni * 16 + (lane & 15)) * HD_ +
                                   (lane >> 4) * 8);
    f32x4 nacc[4][2] = {};
#pragma unroll
    for (int mi = 0; mi < 4; ++mi)
#pragma unroll
        for (int ni = 0; ni < 2; ++ni)
            nacc[mi][ni] = MFMA16(af[mi], bfk[ni], nacc[mi][ni]);

    __syncthreads();   // den_s visible to all waves

    // ---- divide + write swizzled at_s ----
#pragma unroll
    for (int mi = 0; mi < 4; ++mi)
#pragma unroll
        for (int ni = 0; ni < 2; ++ni)
#pragma unroll
            for (int j = 0; j < 4; ++j) {
                const int tok = mi * 16 + (lane >> 4) * 4 + j;
                const int c2 = w * HD_ + ni * 16 + (lane & 15);
                const float a = nacc[mi][ni][j] / den_s[tok][w];
                const int byte = (tok * 512 + c2 * 2) ^ ((tok & 7) << 4);
                *(ushort*)((char*)at_s + byte) = f2bf(a);
            }

    // ---- out GEMM: 8 waves (2x4), wave tile 32 rows x 64 cols; wo from LDS ----
    const int wr = w >> 2, wc = w & 3;
    const int q_ = lane >> 4;
    f32x4 acc[2][4] = {};
    for (int kt = 0; kt < 256; kt += 32) {
        __syncthreads();   // first iteration also covers at_s writes
#pragma unroll
        for (int j = 0; j < 2; ++j) {
            const int ch = j * 512 + t;           // 0..1023
            const int e = ch >> 2;
            const int pslot = ch & 3;
            const int qsrc = pslot ^ ((e >> 1) & 3);
            GLOAD_LDS16(wo + (size_t)e * 256 + kt + qsrc * 8, (char*)Ws2 + ch * 16);
        }
        __syncthreads();
        bf16x8 af2[2];
#pragma unroll
        for (int mm = 0; mm < 2; ++mm) {
            const int r = wr * 32 + mm * 16 + (lane & 15);
            const int byte = (r * 512 + (kt + q_ * 8) * 2) ^ ((r & 7) << 4);
            af2[mm] = *(const bf16x8*)((const char*)at_s + byte);
        }
#pragma unroll
        for (int n = 0; n < 4; ++n) {
            const int e = wc * 64 + n * 16 + (lane & 15);
            const int wbyte = e * 64 + ((q_ ^ ((e >> 1) & 3)) * 16);
            const bf16x8 bw = *(const bf16x8*)((const char*)Ws2 + wbyte);
#pragma unroll
            for (int mm = 0; mm < 2; ++mm)
                acc[mm][n] = MFMA16(af2[mm], bw, acc[mm][n]);
        }
    }
#pragma unroll
    for (int mm = 0; mm < 2; ++mm)
#pragma unroll
        for (int n = 0; n < 4; ++n)
#pragma unroll
            for (int j = 0; j < 4; ++j) {
                const int row = tokBase + wr * 32 + mm * 16 + (lane >> 4) * 4 + j;
                const int col = wc * 64 + n * 16 + (lane & 15);
                out[(size_t)row * 256 + col] = acc[mm][n][j] + bo[col];
            }
}

extern "C" void kernel_launch(void* const* d_in, const int* in_sizes, int n_in,
                              void* d_out, int out_size, void* d_ws, size_t ws_size,
                              hipStream_t stream) {
    const float* x     = (const float*)d_in[0];
    const float* prior = (const float*)d_in[1];
    const float* Wq    = (const float*)d_in[2];
    const float* Wk    = (const float*)d_in[3];
    const float* Wv    = (const float*)d_in[4];
    const float* bv    = (const float*)d_in[5];
    const float* Wo    = (const float*)d_in[6];
    const float* bo    = (const float*)d_in[7];
    float* out = (float*)d_out;

    // workspace layout
    char* w8 = (char*)d_ws;
    ushort* qpre = (ushort*)w8;                         // 8 MB bf16
    ushort* wqb  = qpre + (size_t)TOKENS * D_;          // 4 x 128 KB bf16
    ushort* wkb  = wqb + 65536;
    ushort* wvb  = wkb + 65536;
    ushort* wob  = wvb + 65536;
    ushort* kvbf = wob + 65536;                         // 64 KB bf16 kv summary
    float* ksb   = (float*)(kvbf + 32768);              // 4 KB
    float* bias  = ksb + 1024;                          // 64 KB
    float* part  = bias + TOKENS;                       // 512*8448*4 = 17.3 MB

    k_cvt_w<<<128, 256, 0, stream>>>(Wq, Wk, Wv, Wo, wqb);

    k_mix2<<<2560, 512, 0, stream>>>(prior, x, wqb, wkb, wvb, bv, bias, qpre, part);

    k_kvred<<<132, 256, 0, stream>>>(part, kvbf, ksb);

    k_fusedB<<<256, 512, 0, stream>>>(qpre, bias, kvbf, ksb, wob, bo, out);
}

// Round 25
// 89.360 us; speedup vs baseline: 1.8126x; 1.0321x over previous
//
#include <hip/hip_runtime.h>
#include <hip/hip_bf16.h>
#include <math.h>

#define B_ 4
#define N_ 4096
#define D_ 256
#define H_ 8
#define HD_ 32
#define TOKENS (B_ * N_)   // 16384
#define EPSF 1e-9f

typedef __bf16 bf16x8 __attribute__((ext_vector_type(8)));
typedef float f32x4 __attribute__((ext_vector_type(4)));
typedef ushort ushort8_t __attribute__((ext_vector_type(8)));

__device__ __forceinline__ float elu1(float x) { return x > 0.f ? x + 1.f : __expf(x); }

__device__ __forceinline__ ushort f2bf(float f) {
    __hip_bfloat16 h = __float2bfloat16(f);
    return *reinterpret_cast<ushort*>(&h);
}
__device__ __forceinline__ float bf2f(ushort u) {
    __hip_bfloat16 h = *reinterpret_cast<__hip_bfloat16*>(&u);
    return __bfloat162float(h);
}

#define GLOAD_LDS16(g, l)                                                              \
    __builtin_amdgcn_global_load_lds((__attribute__((address_space(1))) const void*)(g), \
                                     (__attribute__((address_space(3))) void*)(l), 16, 0, 0)

#define MFMA16(a, b, c) __builtin_amdgcn_mfma_f32_16x16x32_bf16((a), (b), (c), 0, 0, 0)

// ---------------- all four W matrices -> bf16, concatenated ----------------
__global__ __launch_bounds__(256) void k_cvt_w(const float* __restrict__ Wq,
                                               const float* __restrict__ Wk,
                                               const float* __restrict__ Wv,
                                               const float* __restrict__ Wo,
                                               ushort* __restrict__ dst) {
    const int i = blockIdx.x * 256 + threadIdx.x;  // 32768 threads x 8 els
    const int sel = i >> 13;
    const float* src = sel == 0 ? Wq : sel == 1 ? Wk : sel == 2 ? Wv : Wo;
    const int j = i & 8191;
    const float4* s = (const float4*)src + (size_t)j * 2;
    const float4 a = s[0], b = s[1];
    ushort8_t o;
    o[0] = f2bf(a.x); o[1] = f2bf(a.y); o[2] = f2bf(a.z); o[3] = f2bf(a.w);
    o[4] = f2bf(b.x); o[5] = f2bf(b.y); o[6] = f2bf(b.z); o[7] = f2bf(b.w);
    *((ushort8_t*)dst + i) = o;
}

// ================= K1: hetero (round-10 proven) + fused kv-partials (bf16) ===========
__global__ __launch_bounds__(512, 2) void k_mix2(const float* __restrict__ prior,
                                                 const float* __restrict__ x,
                                                 const ushort* __restrict__ wq,
                                                 const ushort* __restrict__ wk,
                                                 const ushort* __restrict__ wv,
                                                 const float* __restrict__ bv,
                                                 float* __restrict__ bias_g,
                                                 ushort* __restrict__ qpre,
                                                 ushort* __restrict__ part) {
    __shared__ ushort As[32 * 256];       // 16 KB bf16 x-tile, XOR-swizzled
    __shared__ ushort Ws[3 * 256 * 32];   // 48 KB W slices; reused as VT/KT tiles later
    const int t = threadIdx.x;
    const int w = t >> 6, lane = t & 63;
    const int bid = blockIdx.x;

    if (bid % 5 != 0) {
        // ---- bias block: wave w sums row bidx*8+w (16 KB) with nt loads ----
        const int bidx = bid - bid / 5 - 1;           // 0..2047
        const int row = bidx * 8 + w;
        const f32x4* p = (const f32x4*)(prior + (size_t)row * N_);
        float s0 = 0.f, s1 = 0.f, s2 = 0.f, s3 = 0.f;
#pragma unroll
        for (int i = 0; i < 4; ++i) {
            const f32x4 a = __builtin_nontemporal_load(p + (i * 4 + 0) * 64 + lane);
            const f32x4 b = __builtin_nontemporal_load(p + (i * 4 + 1) * 64 + lane);
            const f32x4 c = __builtin_nontemporal_load(p + (i * 4 + 2) * 64 + lane);
            const f32x4 d = __builtin_nontemporal_load(p + (i * 4 + 3) * 64 + lane);
            s0 += a[0] + a[1] + a[2] + a[3];
            s1 += b[0] + b[1] + b[2] + b[3];
            s2 += c[0] + c[1] + c[2] + c[3];
            s3 += d[0] + d[1] + d[2] + d[3];
        }
        float s = (s0 + s1) + (s2 + s3);
#pragma unroll
        for (int off = 32; off; off >>= 1) s += __shfl_xor(s, off, 64);
        if (lane == 0) bias_g[row] = s * (1.0f / N_);
        return;
    }

    // ---- qkv GEMM tile (round-10 proven body) ----
    const int qidx = bid / 5;             // 0..511
    const int rowBase = qidx * 32;

    {
        const int r = t >> 4;             // 0..31
        const int c0 = (t & 15) * 4;      // 0..60
#pragma unroll
        for (int j = 0; j < 4; ++j) {
            const int c = c0 + j * 64;
            const float4 xv = *(const float4*)(x + (size_t)(rowBase + r) * 256 + c);
            ushort4 o;
            o.x = f2bf(xv.x); o.y = f2bf(xv.y); o.z = f2bf(xv.z); o.w = f2bf(xv.w);
            const int byte = (r * 512 + c * 2) ^ ((r & 7) << 4);
            *(ushort4*)((char*)As + byte) = o;
        }
    }

    const int wr = w >> 2, wc = w & 3;    // 2 x 4 waves; wave tile 16 rows x 64 cols
    const int q_ = lane >> 4;             // k-quarter 0..3
    f32x4 accq[4] = {}, acck[4] = {}, accv[4] = {};

    for (int kt = 0; kt < 256; kt += 32) {
        __syncthreads();   // also covers the A-stage on first iteration
#pragma unroll
        for (int j = 0; j < 6; ++j) {
            const int c = j * 512 + t;            // 0..3071
            const int idx = c & 1023;
            const int e = idx >> 2;
            const int pslot = idx & 3;
            const int qsrc = pslot ^ ((e >> 1) & 3);
            const ushort* srcm = (j < 2) ? wq : (j < 4) ? wk : wv;
            GLOAD_LDS16(srcm + (size_t)e * 256 + kt + qsrc * 8, (char*)Ws + c * 16);
        }
        __syncthreads();
        const int r = wr * 16 + (lane & 15);
        const int abyte = (r * 512 + (kt + q_ * 8) * 2) ^ ((r & 7) << 4);
        const bf16x8 af = *(const bf16x8*)((const char*)As + abyte);
#pragma unroll
        for (int n = 0; n < 4; ++n) {
            const int e = wc * 64 + n * 16 + (lane & 15);
            const int wbyte = e * 64 + ((q_ ^ ((e >> 1) & 3)) * 16);
            const bf16x8 bq = *(const bf16x8*)((const char*)Ws + wbyte);
            const bf16x8 bk = *(const bf16x8*)((const char*)Ws + 16384 + wbyte);
            const bf16x8 bw = *(const bf16x8*)((const char*)Ws + 32768 + wbyte);
            accq[n] = MFMA16(af, bq, accq[n]);
            acck[n] = MFMA16(af, bk, acck[n]);
            accv[n] = MFMA16(af, bw, accv[n]);
        }
    }

    __syncthreads();   // all waves done reading Ws before overlaying VT/KT

    // ---- epilogue: qpre to global; k,v (activated, bf16) into LDS tiles ----
    ushort* VT = Ws;
    ushort* KT = Ws + 8192;
#pragma unroll
    for (int n = 0; n < 4; ++n)
#pragma unroll
        for (int j = 0; j < 4; ++j) {
            const int rl = wr * 16 + (lane >> 4) * 4 + j;    // token t in tile
            const int col = wc * 64 + n * 16 + (lane & 15);  // 0..255
            const size_t go = (size_t)(rowBase + rl) * 256 + col;
            qpre[go] = f2bf(accq[n][j]);
            const int head = col >> 5, dm = col & 31;
            KT[head * 1024 + dm * 32 + rl] = f2bf(elu1(acck[n][j]));
            VT[head * 1024 + dm * 32 + rl] = f2bf(elu1(accv[n][j] + bv[col]));
        }
    __syncthreads();

    // ---- kv partial via MFMA: wave w = head w ----
    const ushort* vtw = VT + w * 1024;
    const ushort* ktw = KT + w * 1024;
    bf16x8 av[2], bk2[2];
#pragma unroll
    for (int i = 0; i < 2; ++i) {
        av[i]  = *(const bf16x8*)(vtw + (i * 16 + (lane & 15)) * 32 + (lane >> 4) * 8);
        bk2[i] = *(const bf16x8*)(ktw + (i * 16 + (lane & 15)) * 32 + (lane >> 4) * 8);
    }
    bf16x8 ones;
#pragma unroll
    for (int i = 0; i < 8; ++i) ones[i] = (__bf16)1.0f;
    f32x4 kvacc[2][2] = {};
    f32x4 ks[2] = {};
#pragma unroll
    for (int mi = 0; mi < 2; ++mi)
#pragma unroll
        for (int di = 0; di < 2; ++di)
            kvacc[mi][di] = MFMA16(av[mi], bk2[di], kvacc[mi][di]);
#pragma unroll
    for (int di = 0; di < 2; ++di) ks[di] = MFMA16(ones, bk2[di], ks[di]);

    // partials stored bf16: all addends positive (elu1 outputs) -> no cancellation;
    // 128-way sum of bf16-rounded partials adds ~0.04% relative error.
    ushort* pp = part + (size_t)qidx * 8448 + w * 1056;
#pragma unroll
    for (int mi = 0; mi < 2; ++mi)
#pragma unroll
        for (int di = 0; di < 2; ++di)
#pragma unroll
            for (int j = 0; j < 4; ++j) {
                const int m = mi * 16 + (lane >> 4) * 4 + j;
                const int d = di * 16 + (lane & 15);
                pp[m * 32 + d] = f2bf(kvacc[mi][di][j]);
            }
    if ((lane >> 4) == 0) {
        pp[1024 + (lane & 15)] = f2bf(ks[0][0]);
        pp[1024 + 16 + (lane & 15)] = f2bf(ks[1][0]);
    }
}

// ---------------- reduce 128 chunk-partials per (b,h); kv -> bf16, ksum -> fp32 ------
__global__ __launch_bounds__(256) void k_kvred(const ushort* __restrict__ part,
                                               ushort* __restrict__ kvbf,
                                               float* __restrict__ ksum) {
    const int i = blockIdx.x * 256 + threadIdx.x;   // 0..33791 (132*256)
    if (i >= 32 * 1056) return;
    const int bh = i / 1056, r = i - bh * 1056;
    const int b = bh >> 3, h = bh & 7;
    float s = 0.f;
#pragma unroll 8
    for (int c = 0; c < 128; ++c)
        s += bf2f(part[(size_t)(b * 128 + c) * 8448 + h * 1056 + r]);
    if (r < 1024) kvbf[(size_t)bh * 1024 + r] = f2bf(s);
    else          ksum[(size_t)bh * 32 + (r - 1024)] = s;
}

// ================= K3: q-finalize + MFMA attn + out-GEMM =================
__global__ __launch_bounds__(512, 2) void k_fusedB(const ushort* __restrict__ qpre,
                                                   const float* __restrict__ bias_g,
                                                   const ushort* __restrict__ kvbf,
                                                   const float* __restrict__ ksum,
                                                   const ushort* __restrict__ wo,
                                                   const float* __restrict__ bo,
                                                   float* __restrict__ out) {
    __shared__ ushort qs[64 * 256];    // linear bf16 q tile (32 KB)
    __shared__ ushort at_s[64 * 256];  // swizzled bf16 attn tile (32 KB)
    __shared__ ushort Ws2[256 * 32];   // 16 KB wo slice, slot-swizzled
    __shared__ float den_s[64][8];     // 2 KB
    const int t = threadIdx.x;
    const int w = t >> 6, lane = t & 63;
    const int tokBase = blockIdx.x * 64;
    const int b = tokBase >> 12;

#pragma unroll
    for (int j = 0; j < 4; ++j) {
        const int chunk = j * 512 + t;
        GLOAD_LDS16(qpre + (size_t)tokBase * 256 + (size_t)chunk * 8,
                    (char*)qs + chunk * 16);
    }
    __syncthreads();

    // ---- q finalize in-place ----
    {
        const int r = t >> 3;
        const float brow = bias_g[tokBase + r];
        const int cb = (t & 7) * 32;
#pragma unroll
        for (int i = 0; i < 4; ++i) {
            bf16x8 qv = *(bf16x8*)(qs + r * 256 + cb + i * 8);
#pragma unroll
            for (int j = 0; j < 8; ++j) qv[j] = (__bf16)elu1((float)qv[j] + brow);
            *(bf16x8*)(qs + r * 256 + cb + i * 8) = qv;
        }
    }
    __syncthreads();

    // ---- denominator: den_s[tok][h] = q[tok][h,:] . ksum[b,h,:] + eps ----
    {
        const int tok = t >> 3, h = t & 7;
        const float* ksp = ksum + (size_t)(b * H_ + h) * HD_;
        float den = 0.f;
#pragma unroll
        for (int i = 0; i < 4; ++i) {
            const bf16x8 qv = *(const bf16x8*)(qs + tok * 256 + h * HD_ + i * 8);
            const f32x4 k0 = *(const f32x4*)(ksp + i * 8);
            const f32x4 k1 = *(const f32x4*)(ksp + i * 8 + 4);
#pragma unroll
            for (int j = 0; j < 4; ++j) {
                den = fmaf((float)qv[j], k0[j], den);
                den = fmaf((float)qv[j + 4], k1[j], den);
            }
        }
        den_s[tok][h] = den + EPSF;
    }

    // ---- numerator via MFMA: wave w = head w; Q[64x32] x kv_h[32x32]^T ----
    bf16x8 af[4], bfk[2];
#pragma unroll
    for (int mi = 0; mi < 4; ++mi)
        af[mi] = *(const bf16x8*)(qs + (mi * 16 + (lane & 15)) * 256 + w * HD_ +
                                  (lane >> 4) * 8);
#pragma unroll
    for (int ni = 0; ni < 2; ++ni)
        bfk[ni] = *(const bf16x8*)(kvbf +
                                   ((size_t)(b * H_ + w) * HD_ + ni * 16 + (lane & 15)) * HD_ +
                                   (lane >> 4) * 8);
    f32x4 nacc[4][2] = {};
#pragma unroll
    for (int mi = 0; mi < 4; ++mi)
#pragma unroll
        for (int ni = 0; ni < 2; ++ni)
            nacc[mi][ni] = MFMA16(af[mi], bfk[ni], nacc[mi][ni]);

    __syncthreads();   // den_s visible to all waves

    // ---- divide + write swizzled at_s ----
#pragma unroll
    for (int mi = 0; mi < 4; ++mi)
#pragma unroll
        for (int ni = 0; ni < 2; ++ni)
#pragma unroll
            for (int j = 0; j < 4; ++j) {
                const int tok = mi * 16 + (lane >> 4) * 4 + j;
                const int c2 = w * HD_ + ni * 16 + (lane & 15);
                const float a = nacc[mi][ni][j] / den_s[tok][w];
                const int byte = (tok * 512 + c2 * 2) ^ ((tok & 7) << 4);
                *(ushort*)((char*)at_s + byte) = f2bf(a);
            }

    // ---- out GEMM: 8 waves (2x4), wave tile 32 rows x 64 cols; wo from LDS ----
    const int wr = w >> 2, wc = w & 3;
    const int q_ = lane >> 4;
    f32x4 acc[2][4] = {};
    for (int kt = 0; kt < 256; kt += 32) {
        __syncthreads();   // first iteration also covers at_s writes
#pragma unroll
        for (int j = 0; j < 2; ++j) {
            const int ch = j * 512 + t;           // 0..1023
            const int e = ch >> 2;
            const int pslot = ch & 3;
            const int qsrc = pslot ^ ((e >> 1) & 3);
            GLOAD_LDS16(wo + (size_t)e * 256 + kt + qsrc * 8, (char*)Ws2 + ch * 16);
        }
        __syncthreads();
        bf16x8 af2[2];
#pragma unroll
        for (int mm = 0; mm < 2; ++mm) {
            const int r = wr * 32 + mm * 16 + (lane & 15);
            const int byte = (r * 512 + (kt + q_ * 8) * 2) ^ ((r & 7) << 4);
            af2[mm] = *(const bf16x8*)((const char*)at_s + byte);
        }
#pragma unroll
        for (int n = 0; n < 4; ++n) {
            const int e = wc * 64 + n * 16 + (lane & 15);
            const int wbyte = e * 64 + ((q_ ^ ((e >> 1) & 3)) * 16);
            const bf16x8 bw = *(const bf16x8*)((const char*)Ws2 + wbyte);
#pragma unroll
            for (int mm = 0; mm < 2; ++mm)
                acc[mm][n] = MFMA16(af2[mm], bw, acc[mm][n]);
        }
    }
#pragma unroll
    for (int mm = 0; mm < 2; ++mm)
#pragma unroll
        for (int n = 0; n < 4; ++n)
#pragma unroll
            for (int j = 0; j < 4; ++j) {
                const int row = tokBase + wr * 32 + mm * 16 + (lane >> 4) * 4 + j;
                const int col = wc * 64 + n * 16 + (lane & 15);
                out[(size_t)row * 256 + col] = acc[mm][n][j] + bo[col];
            }
}

extern "C" void kernel_launch(void* const* d_in, const int* in_sizes, int n_in,
                              void* d_out, int out_size, void* d_ws, size_t ws_size,
                              hipStream_t stream) {
    const float* x     = (const float*)d_in[0];
    const float* prior = (const float*)d_in[1];
    const float* Wq    = (const float*)d_in[2];
    const float* Wk    = (const float*)d_in[3];
    const float* Wv    = (const float*)d_in[4];
    const float* bv    = (const float*)d_in[5];
    const float* Wo    = (const float*)d_in[6];
    const float* bo    = (const float*)d_in[7];
    float* out = (float*)d_out;

    // workspace layout
    char* w8 = (char*)d_ws;
    ushort* qpre = (ushort*)w8;                         // 8 MB bf16
    ushort* wqb  = qpre + (size_t)TOKENS * D_;          // 4 x 128 KB bf16
    ushort* wkb  = wqb + 65536;
    ushort* wvb  = wkb + 65536;
    ushort* wob  = wvb + 65536;
    ushort* kvbf = wob + 65536;                         // 64 KB bf16 kv summary
    float* ksb   = (float*)(kvbf + 32768);              // 4 KB
    float* bias  = ksb + 1024;                          // 64 KB
    ushort* part = (ushort*)(bias + TOKENS);            // 512*8448*2 = 8.65 MB bf16

    k_cvt_w<<<128, 256, 0, stream>>>(Wq, Wk, Wv, Wo, wqb);

    k_mix2<<<2560, 512, 0, stream>>>(prior, x, wqb, wkb, wvb, bv, bias, qpre, part);

    k_kvred<<<132, 256, 0, stream>>>(part, kvbf, ksb);

    k_fusedB<<<256, 512, 0, stream>>>(qpre, bias, kvbf, ksb, wob, bo, out);
}